// Round 2
// baseline (21380.551 us; speedup 1.0000x reference)
//
#include <hip/hip_runtime.h>
#include <math.h>

#define KTOK 30      // tokens per node
#define HIDC 100     // hidden channels
#define EDIM 200     // TCH + IN_CH

// ---------------------------------------------------------------- bf16 helpers
__device__ __forceinline__ unsigned short f2bf(float f) {
    unsigned u = __float_as_uint(f);
    unsigned r = (u + 0x7FFFu + ((u >> 16) & 1u)) >> 16;
    return (unsigned short)r;
}
__device__ __forceinline__ float bf2f(unsigned short h) {
    return __uint_as_float(((unsigned)h) << 16);
}
__device__ __forceinline__ float gelu_exact(float x) {
    return 0.5f * x * (1.0f + erff(x * 0.70710678118654752f));
}

// ---------------------------------------------------------------- kernel 1: count edges per node
__global__ void count_kernel(const int* __restrict__ nb, int* __restrict__ cnt, int E) {
    int e = blockIdx.x * blockDim.x + threadIdx.x;
    if (e < E) atomicAdd(&cnt[nb[e]], 1);
}

// ---------------------------------------------------------------- kernel 2: exclusive scan (single block)
#define SCAN_T 1024
__global__ void scan_kernel(const int* __restrict__ cnt, int* __restrict__ offsets, int n) {
    __shared__ int sd[SCAN_T];
    __shared__ int srun;
    if (threadIdx.x == 0) srun = 0;
    __syncthreads();
    for (int base = 0; base < n; base += SCAN_T) {
        int i = base + threadIdx.x;
        int v = (i < n) ? cnt[i] : 0;
        sd[threadIdx.x] = v;
        __syncthreads();
        for (int off = 1; off < SCAN_T; off <<= 1) {
            int tv = (threadIdx.x >= off) ? sd[threadIdx.x - off] : 0;
            __syncthreads();
            sd[threadIdx.x] += tv;
            __syncthreads();
        }
        if (i < n) offsets[i] = srun + sd[threadIdx.x] - v;
        int bsum = sd[SCAN_T - 1];
        __syncthreads();
        if (threadIdx.x == 0) srun += bsum;
        __syncthreads();
    }
}

// ---------------------------------------------------------------- kernel 3: bucket fill
__global__ void fill_kernel(const int* __restrict__ nb, int* __restrict__ cursor,
                            const int* __restrict__ offsets, int* __restrict__ order, int E) {
    int e = blockIdx.x * blockDim.x + threadIdx.x;
    if (e >= E) return;
    int n = nb[e];
    int p = atomicAdd(&cursor[n], 1);
    order[offsets[n] + p] = e;
}

// ---------------------------------------------------------------- kernel 4: per-node K smallest edge ids
__global__ void select_kernel(const int* __restrict__ cnt, const int* __restrict__ offsets,
                              const int* __restrict__ order, int* __restrict__ sel, int N) {
    int node = blockIdx.x * blockDim.x + threadIdx.x;
    if (node >= N) return;
    int c = cnt[node];
    int off = offsets[node];
    int top[KTOK];
    int m = 0;
    for (int i = 0; i < c; i++) {
        int e = order[off + i];
        if (m < KTOK) {
            int j = m++;
            while (j > 0 && top[j - 1] > e) { top[j] = top[j - 1]; j--; }
            top[j] = e;
        } else if (e < top[KTOK - 1]) {
            int j = KTOK - 1;
            while (j > 0 && top[j - 1] > e) { top[j] = top[j - 1]; j--; }
            top[j] = e;
        }
    }
    for (int p = 0; p < KTOK; p++) sel[node * KTOK + p] = (p < m) ? top[p] : -1;
}

// ---------------------------------------------------------------- kernel 5: weight prep (transpose + LN_c fold)
__global__ void prep_kernel(const float* __restrict__ head_w,
                            const float* __restrict__ ch1_w, const float* __restrict__ ch1_b,
                            const float* __restrict__ ch2_w,
                            const float* __restrict__ ln_c_g, const float* __restrict__ ln_c_b,
                            float* __restrict__ head_wT, float* __restrict__ wg1T,
                            float* __restrict__ w2T, float* __restrict__ Sg1,
                            float* __restrict__ b1p) {
    int i = blockIdx.x * blockDim.x + threadIdx.x;
    if (i < 20000) { int c = i / 100, o = i - c * 100; head_wT[c * 100 + o] = head_w[o * 200 + c]; }
    if (i < 40000) { int c = i / 400, o = i - c * 400; wg1T[c * 400 + o] = ch1_w[o * 100 + c] * ln_c_g[c]; }
    if (i < 40000) { int h = i / 100, j = i - h * 100; w2T[h * 100 + j] = ch2_w[j * 400 + h]; }
    if (i < 400) {
        float sg = 0.f, sb = 0.f;
        for (int c = 0; c < 100; c++) {
            float w = ch1_w[i * 100 + c];
            sg += w * ln_c_g[c];
            sb += w * ln_c_b[c];
        }
        Sg1[i] = sg;
        b1p[i] = sb + ch1_b[i];
    }
}

// ---------------------------------------------------------------- kernel 6: fused per-node forward
// One wave (64 threads) per block; lanes 0-29 = node A tokens, 32-61 = node B tokens.
// All matmuls: weights via uniform scalar loads (SGPR), activations in VGPRs.
__global__ __launch_bounds__(64, 2) void fused_node_kernel(
    const float* __restrict__ edge_attr, const float* __restrict__ edge_time,
    const int* __restrict__ sel,
    const float* __restrict__ head_wT, const float* __restrict__ head_b,
    const float* __restrict__ ln_t_g, const float* __restrict__ ln_t_b,
    const float* __restrict__ tok1_w, const float* __restrict__ tok1_b,
    const float* __restrict__ tok2_w, const float* __restrict__ tok2_b,
    const float* __restrict__ wg1T, const float* __restrict__ Sg1, const float* __restrict__ b1p,
    const float* __restrict__ w2T, const float* __restrict__ ch2_b,
    const float* __restrict__ ln_h_g, const float* __restrict__ ln_h_b,
    const float* __restrict__ out_w, const float* __restrict__ out_b,
    float* __restrict__ out, int N) {

    __shared__ unsigned short buf[100 * 64];   // [c][col], col = lane (A: 0-29, B: 32-61)
    __shared__ float tbuf[2][100];

    const int lane = threadIdx.x;
    const int half = lane >> 5;
    const int tk = lane & 31;
    const int node = blockIdx.x * 2 + half;
    const bool valid = (tk < KTOK) && (node < N);

    int e = valid ? sel[node * KTOK + tk] : -1;
    const bool ev = (e >= 0);
    const int eS = ev ? e : 0;
    const float time = edge_time[eS];

    float act[HIDC];
    #pragma unroll
    for (int o = 0; o < HIDC; o++) act[o] = 0.f;

    // ---- head, temporal part: c = 0..99, IN[c] = cos(time * 10^(-10c/99))
    for (int c = 0; c < 100; c++) {
        float tw = exp2f(-0.33554829241286486f * (float)c);
        float inv = __cosf(time * tw);
        const float* w = head_wT + c * 100;           // uniform -> s_load
        #pragma unroll
        for (int o = 0; o < HIDC; o++) act[o] = fmaf(w[o], inv, act[o]);
    }
    // ---- head, edge_attr part: c = 100..199
    {
        const float* arow = edge_attr + (size_t)eS * 100;
        for (int c4 = 0; c4 < 100; c4 += 4) {
            float4 v = *(const float4*)(arow + c4);
            float vv[4] = {v.x, v.y, v.z, v.w};
            #pragma unroll
            for (int q = 0; q < 4; q++) {
                const float* w = head_wT + (100 + c4 + q) * 100;  // uniform -> s_load
                #pragma unroll
                for (int o = 0; o < HIDC; o++) act[o] = fmaf(w[o], vv[q], act[o]);
            }
        }
    }
    #pragma unroll
    for (int o = 0; o < HIDC; o++) act[o] = ev ? (act[o] + head_b[o]) : 0.f;

    // ---- LN_t (per-lane over registers) -> bf16 transpose into LDS
    {
        float s = 0.f;
        #pragma unroll
        for (int c = 0; c < HIDC; c++) s += act[c];
        float m = s * 0.01f;
        float s2 = 0.f;
        #pragma unroll
        for (int c = 0; c < HIDC; c++) { float d = act[c] - m; s2 = fmaf(d, d, s2); }
        float rs = rsqrtf(s2 * 0.01f + 1e-5f);
        #pragma unroll
        for (int c = 0; c < HIDC; c++) {
            float lnv = (act[c] - m) * rs * ln_t_g[c] + ln_t_b[c];
            if (valid) buf[c * 64 + lane] = f2bf(lnv);
        }
    }
    __syncthreads();

    // ---- token mixer: 200 tasks = (channel, half); in-place row rewrite
    for (int r = 0; r < 4; r++) {
        int task = r * 64 + lane;
        if (task < 200) {
            int c = task >> 1;
            int h = task & 1;
            unsigned short* row = &buf[c * 64 + h * 32];
            float v[KTOK];
            {
                const ushort4* p4 = reinterpret_cast<const ushort4*>(row);
                #pragma unroll
                for (int q = 0; q < 7; q++) {
                    ushort4 u = p4[q];
                    v[q * 4 + 0] = bf2f(u.x); v[q * 4 + 1] = bf2f(u.y);
                    v[q * 4 + 2] = bf2f(u.z); v[q * 4 + 3] = bf2f(u.w);
                }
                ushort2 u2 = *reinterpret_cast<const ushort2*>(row + 28);
                v[28] = bf2f(u2.x); v[29] = bf2f(u2.y);
            }
            float y[15];
            #pragma unroll
            for (int i = 0; i < 15; i++) {
                float a = tok1_b[i];
                #pragma unroll
                for (int k = 0; k < KTOK; k++) a = fmaf(tok1_w[i * KTOK + k], v[k], a);
                y[i] = gelu_exact(a);
            }
            float ov[KTOK];
            #pragma unroll
            for (int k = 0; k < KTOK; k++) {
                float a = tok2_b[k];
                #pragma unroll
                for (int i = 0; i < 15; i++) a = fmaf(tok2_w[k * 15 + i], y[i], a);
                ov[k] = a;
            }
            unsigned int* wrow = reinterpret_cast<unsigned int*>(row);
            #pragma unroll
            for (int k = 0; k < 15; k++)
                wrow[k] = (unsigned)f2bf(ov[2 * k]) | ((unsigned)f2bf(ov[2 * k + 1]) << 16);
        }
    }
    __syncthreads();

    // ---- h_token = mixer_out + x  (read back transpose)
    #pragma unroll
    for (int c = 0; c < HIDC; c++) act[c] += bf2f(buf[c * 64 + lane]);

    // ---- LN_c stats (fold into ch1 via prepped weights)
    float m2, rs2;
    {
        float s = 0.f;
        #pragma unroll
        for (int c = 0; c < HIDC; c++) s += act[c];
        m2 = s * 0.01f;
        float s2 = 0.f;
        #pragma unroll
        for (int c = 0; c < HIDC; c++) { float d = act[c] - m2; s2 = fmaf(d, d, s2); }
        rs2 = rsqrtf(s2 * 0.01f + 1e-5f);
    }

    // ---- channel mixer, fused ch1 -> gelu -> ch2 (h-chunks of 8)
    {
        float acc2[HIDC];
        #pragma unroll
        for (int j = 0; j < HIDC; j++) acc2[j] = 0.f;
        for (int o8 = 0; o8 < 400; o8 += 8) {
            float a1[8];
            #pragma unroll
            for (int j = 0; j < 8; j++) a1[j] = 0.f;
            #pragma unroll
            for (int c = 0; c < HIDC; c++) {
                const float* wc = wg1T + c * 400 + o8;   // uniform -> s_load (8 consecutive)
                #pragma unroll
                for (int j = 0; j < 8; j++) a1[j] = fmaf(wc[j], act[c], a1[j]);
            }
            #pragma unroll
            for (int j = 0; j < 8; j++) {
                float h1 = fmaf(rs2, fmaf(-m2, Sg1[o8 + j], a1[j]), b1p[o8 + j]);
                a1[j] = gelu_exact(h1);
            }
            #pragma unroll
            for (int hh = 0; hh < 8; hh++) {
                const float* w2r = w2T + (o8 + hh) * 100;  // uniform -> s_load
                float g = a1[hh];
                #pragma unroll
                for (int j = 0; j < HIDC; j++) acc2[j] = fmaf(w2r[j], g, acc2[j]);
            }
        }
        #pragma unroll
        for (int j = 0; j < HIDC; j++) act[j] += acc2[j] + ch2_b[j];  // h_channel
    }

    // ---- LN_h -> bf16 transpose
    {
        float s = 0.f;
        #pragma unroll
        for (int c = 0; c < HIDC; c++) s += act[c];
        float m3 = s * 0.01f;
        float s2 = 0.f;
        #pragma unroll
        for (int c = 0; c < HIDC; c++) { float d = act[c] - m3; s2 = fmaf(d, d, s2); }
        float rs3 = rsqrtf(s2 * 0.01f + 1e-5f);
        #pragma unroll
        for (int c = 0; c < HIDC; c++) {
            float lnv = (act[c] - m3) * rs3 * ln_h_g[c] + ln_h_b[c];
            if (valid) buf[c * 64 + lane] = f2bf(lnv);
        }
    }
    __syncthreads();

    // ---- mean over tokens (column sums)
    for (int r = 0; r < 4; r++) {
        int task = r * 64 + lane;
        if (task < 200) {
            int c = task >> 1;
            int h = task & 1;
            const unsigned short* row = &buf[c * 64 + h * 32];
            float s = 0.f;
            const ushort4* p4 = reinterpret_cast<const ushort4*>(row);
            #pragma unroll
            for (int q = 0; q < 7; q++) {
                ushort4 u = p4[q];
                s += bf2f(u.x) + bf2f(u.y) + bf2f(u.z) + bf2f(u.w);
            }
            ushort2 u2 = *reinterpret_cast<const ushort2*>(row + 28);
            s += bf2f(u2.x) + bf2f(u2.y);
            tbuf[h][c] = s * (1.0f / 30.0f);
        }
    }
    __syncthreads();

    // ---- output matmul: 200 tasks = (o, half)
    for (int r = 0; r < 4; r++) {
        int task = r * 64 + lane;
        if (task < 200) {
            int o = task >> 1;
            int h = task & 1;
            int nd = blockIdx.x * 2 + h;
            if (nd < N) {
                float a = out_b[o];
                const float* wr = out_w + o * 100;
                const float* tv = tbuf[h];
                for (int c = 0; c < 100; c += 4) {
                    float4 w4 = *(const float4*)(wr + c);
                    float4 t4 = *(const float4*)(tv + c);
                    a += w4.x * t4.x + w4.y * t4.y + w4.z * t4.z + w4.w * t4.w;
                }
                out[(size_t)nd * 100 + o] = a;
            }
        }
    }
}

// ---------------------------------------------------------------- launch

extern "C" void kernel_launch(void* const* d_in, const int* in_sizes, int n_in,
                              void* d_out, int out_size, void* d_ws, size_t ws_size,
                              hipStream_t stream) {
    const float* edge_attr  = (const float*)d_in[0];
    const float* edge_time  = (const float*)d_in[1];
    const int*   node_batch = (const int*)d_in[2];
    const float* head_w = (const float*)d_in[4];
    const float* head_b = (const float*)d_in[5];
    const float* ln_t_g = (const float*)d_in[6];
    const float* ln_t_b = (const float*)d_in[7];
    const float* tok1_w = (const float*)d_in[8];
    const float* tok1_b = (const float*)d_in[9];
    const float* tok2_w = (const float*)d_in[10];
    const float* tok2_b = (const float*)d_in[11];
    const float* ln_c_g = (const float*)d_in[12];
    const float* ln_c_b = (const float*)d_in[13];
    const float* ch1_w  = (const float*)d_in[14];
    const float* ch1_b  = (const float*)d_in[15];
    const float* ch2_w  = (const float*)d_in[16];
    const float* ch2_b  = (const float*)d_in[17];
    const float* ln_h_g = (const float*)d_in[18];
    const float* ln_h_b = (const float*)d_in[19];
    const float* out_w  = (const float*)d_in[20];
    const float* out_b  = (const float*)d_in[21];
    float* out = (float*)d_out;

    const int E = in_sizes[2];
    const int N = out_size / HIDC;

    int* cnt     = (int*)d_ws;                 // N
    int* cursor  = cnt + N;                    // N
    int* offsets = cursor + N;                 // N
    int* order   = offsets + N;                // E
    int* sel     = order + E;                  // N*K
    float* head_wT = (float*)(sel + (size_t)N * KTOK);  // 200*100
    float* wg1T    = head_wT + 20000;          // 100*400
    float* w2T     = wg1T + 40000;             // 400*100
    float* Sg1     = w2T + 40000;              // 400
    float* b1p     = Sg1 + 400;                // 400

    hipMemsetAsync(cnt, 0, (size_t)2 * N * sizeof(int), stream);
    count_kernel<<<(E + 255) / 256, 256, 0, stream>>>(node_batch, cnt, E);
    scan_kernel<<<1, SCAN_T, 0, stream>>>(cnt, offsets, N);
    fill_kernel<<<(E + 255) / 256, 256, 0, stream>>>(node_batch, cursor, offsets, order, E);
    select_kernel<<<(N + 255) / 256, 256, 0, stream>>>(cnt, offsets, order, sel, N);
    prep_kernel<<<157, 256, 0, stream>>>(head_w, ch1_w, ch1_b, ch2_w, ln_c_g, ln_c_b,
                                         head_wT, wg1T, w2T, Sg1, b1p);
    fused_node_kernel<<<(N + 1) / 2, 64, 0, stream>>>(
        edge_attr, edge_time, sel, head_wT, head_b,
        ln_t_g, ln_t_b, tok1_w, tok1_b, tok2_w, tok2_b,
        wg1T, Sg1, b1p, w2T, ch2_b, ln_h_g, ln_h_b,
        out_w, out_b, out, N);
}

// Round 3
// 1635.405 us; speedup vs baseline: 13.0736x; 13.0736x over previous
//
#include <hip/hip_runtime.h>
#include <math.h>

#define KTOK 30
#define HIDC 100
#define NPB  4            // nodes per block
#define SCAN_T 1024

typedef short s16x8 __attribute__((ext_vector_type(8)));
typedef float f32x4 __attribute__((ext_vector_type(4)));

// ---------------------------------------------------------------- helpers
__device__ __forceinline__ unsigned short f2bf(float f) {
    unsigned u = __float_as_uint(f);
    unsigned r = (u + 0x7FFFu + ((u >> 16) & 1u)) >> 16;
    return (unsigned short)r;
}
__device__ __forceinline__ float bf2f(unsigned short h) {
    return __uint_as_float(((unsigned)h) << 16);
}
// tanh-form GELU (max abs err ~3e-4 vs exact erf form)
__device__ __forceinline__ float gelu(float x) {
    float u = x * (1.5957691216057308f + 0.07135481627159720f * x * x);
    float e = __expf(-u);
    return x * __builtin_amdgcn_rcpf(1.0f + e);
}

// ---------------------------------------------------------------- selection pipeline
__global__ void count_kernel(const int* __restrict__ nb, int* __restrict__ cnt, int E) {
    int e = blockIdx.x * blockDim.x + threadIdx.x;
    if (e < E) atomicAdd(&cnt[nb[e]], 1);
}

__global__ void scan_kernel(const int* __restrict__ cnt, int* __restrict__ offsets, int n) {
    __shared__ int sd[SCAN_T];
    __shared__ int srun;
    if (threadIdx.x == 0) srun = 0;
    __syncthreads();
    for (int base = 0; base < n; base += SCAN_T) {
        int i = base + threadIdx.x;
        int v = (i < n) ? cnt[i] : 0;
        sd[threadIdx.x] = v;
        __syncthreads();
        for (int off = 1; off < SCAN_T; off <<= 1) {
            int tv = (threadIdx.x >= off) ? sd[threadIdx.x - off] : 0;
            __syncthreads();
            sd[threadIdx.x] += tv;
            __syncthreads();
        }
        if (i < n) offsets[i] = srun + sd[threadIdx.x] - v;
        int bsum = sd[SCAN_T - 1];
        __syncthreads();
        if (threadIdx.x == 0) srun += bsum;
        __syncthreads();
    }
}

__global__ void fill_kernel(const int* __restrict__ nb, int* __restrict__ cursor,
                            const int* __restrict__ offsets, int* __restrict__ order, int E) {
    int e = blockIdx.x * blockDim.x + threadIdx.x;
    if (e >= E) return;
    int n = nb[e];
    int p = atomicAdd(&cursor[n], 1);
    order[offsets[n] + p] = e;
}

__global__ void select_kernel(const int* __restrict__ cnt, const int* __restrict__ offsets,
                              const int* __restrict__ order, int* __restrict__ sel, int N) {
    int node = blockIdx.x * blockDim.x + threadIdx.x;
    if (node >= N) return;
    int c = cnt[node];
    int off = offsets[node];
    int top[KTOK];
    int m = 0;
    for (int i = 0; i < c; i++) {
        int e = order[off + i];
        if (m < KTOK) {
            int j = m++;
            while (j > 0 && top[j - 1] > e) { top[j] = top[j - 1]; j--; }
            top[j] = e;
        } else if (e < top[KTOK - 1]) {
            int j = KTOK - 1;
            while (j > 0 && top[j - 1] > e) { top[j] = top[j - 1]; j--; }
            top[j] = e;
        }
    }
    for (int p = 0; p < KTOK; p++) sel[node * KTOK + p] = (p < m) ? top[p] : -1;
}

// ---------------------------------------------------------------- weight fragment prep
// B-fragment layout for mfma_f32_16x16x32_bf16: lane l, elem i holds B[kt*32+(l>>4)*8+i][nt*16+(l&15)]
// Buffers (ushort elems): headWf[8][7][64][8] @0 ; wg1f[4][25][64][8] @28672 ;
//                         w2f[13][7][64][8] @79872 ; tok1f[64][8] @126464 ; tok2f[2][64][8] @126976
__global__ void prep_kernel(const float* __restrict__ head_w, const float* __restrict__ ch1_w,
                            const float* __restrict__ ch2_w, const float* __restrict__ tok1_w,
                            const float* __restrict__ tok2_w, unsigned short* __restrict__ wf) {
    int i = blockIdx.x * blockDim.x + threadIdx.x;
    if (i >= 128000) return;
    float val = 0.0f;
    if (i < 28672) {                       // headWf: B[k][n] = head_w[n][k], k<200,n<100
        int ii = i & 7, lane = (i >> 3) & 63, rest = i >> 9;
        int nt = rest % 7, kt = rest / 7;
        int k = kt * 32 + ((lane >> 4) << 3) + ii;
        int n = nt * 16 + (lane & 15);
        if (k < 200 && n < 100) val = head_w[n * 200 + k];
    } else if (i < 79872) {                // wg1f: B[k][n] = ch1_w[n][k], k<100,n<400
        int j = i - 28672;
        int ii = j & 7, lane = (j >> 3) & 63, rest = j >> 9;
        int nt = rest % 25, kt = rest / 25;
        int k = kt * 32 + ((lane >> 4) << 3) + ii;
        int n = nt * 16 + (lane & 15);
        if (k < 100) val = ch1_w[n * 100 + k];
    } else if (i < 126464) {               // w2f: B[k][n] = ch2_w[n][k], k<400,n<100
        int j = i - 79872;
        int ii = j & 7, lane = (j >> 3) & 63, rest = j >> 9;
        int nt = rest % 7, kt = rest / 7;
        int k = kt * 32 + ((lane >> 4) << 3) + ii;
        int n = nt * 16 + (lane & 15);
        if (k < 400 && n < 100) val = ch2_w[n * 400 + k];
    } else if (i < 126976) {               // tok1f: B[k][n] = tok1_w[n][k], k<30,n<15
        int j = i - 126464;
        int ii = j & 7, lane = (j >> 3) & 63;
        int k = ((lane >> 4) << 3) + ii;
        int n = lane & 15;
        if (k < 30 && n < 15) val = tok1_w[n * 30 + k];
    } else {                               // tok2f: B[k][n] = tok2_w[n][k], k<15,n<30
        int j = i - 126976;
        int ii = j & 7, lane = (j >> 3) & 63, nt = j >> 9;
        int k = ((lane >> 4) << 3) + ii;
        int n = nt * 16 + (lane & 15);
        if (k < 15 && n < 30) val = tok2_w[n * 15 + k];
    }
    wf[i] = f2bf(val);
}

// ---------------------------------------------------------------- LayerNorm over LDS rows
// 2 threads per row; stride 104 (cols 100..103 must be zero in src).
// writeMode: normalized (with g,b from GLOBAL) -> dst (stride 104, zeros cols 100..103)
// statsMode (mrsOut != null): writes m, rs to mrsOut[row*2 .. +1]
__device__ __forceinline__ void ln_pass(const unsigned short* src, unsigned short* dst,
                                        const float* __restrict__ g, const float* __restrict__ b,
                                        float* mrsOut, int t) {
    const int row = t >> 1, half = t & 1;
    const int nw = half ? 7 : 6;           // half0: cols 0..47 (6x b128), half1: 48..103 (7x b128)
    const s16x8* p = (const s16x8*)(src + row * 104 + half * 48);
    float vals[56];
    float s = 0.f, s2 = 0.f;
    #pragma unroll
    for (int q = 0; q < 7; q++) {
        if (q < nw) {
            s16x8 u = p[q];
            #pragma unroll
            for (int i2 = 0; i2 < 8; i2++) {
                float f = bf2f((unsigned short)u[i2]);
                vals[q * 8 + i2] = f;
                s += f;
                s2 = fmaf(f, f, s2);
            }
        }
    }
    s += __shfl_xor(s, 1);
    s2 += __shfl_xor(s2, 1);
    float m = s * 0.01f;
    float var = fmaxf(s2 * 0.01f - m * m, 0.f);
    float rs = rsqrtf(var + 1e-5f);
    if (mrsOut) {
        if (!half) { mrsOut[row * 2] = m; mrsOut[row * 2 + 1] = rs; }
        return;
    }
    const int c0 = half * 48;
    #pragma unroll
    for (int q = 0; q < 7; q++) {
        if (q < nw) {
            #pragma unroll
            for (int i2 = 0; i2 < 8; i2 += 2) {
                int col = c0 + q * 8 + i2;
                float f0 = (col < 100)     ? (vals[q * 8 + i2]     - m) * rs * g[col]     + b[col]     : 0.f;
                float f1 = (col + 1 < 100) ? (vals[q * 8 + i2 + 1] - m) * rs * g[col + 1] + b[col + 1] : 0.f;
                *(unsigned*)&dst[row * 104 + col] = (unsigned)f2bf(f0) | ((unsigned)f2bf(f1) << 16);
            }
        }
    }
}

// ---------------------------------------------------------------- fused per-node forward (MFMA)
__global__ __launch_bounds__(256, 2) void fused_node_kernel(
    const float* __restrict__ edge_attr, const float* __restrict__ edge_time,
    const int* __restrict__ sel, const unsigned short* __restrict__ wf,
    const float* __restrict__ head_b,
    const float* __restrict__ ln_t_g, const float* __restrict__ ln_t_b,
    const float* __restrict__ tok1_b, const float* __restrict__ tok2_b,
    const float* __restrict__ ln_c_g, const float* __restrict__ ln_c_b,
    const float* __restrict__ ch1_b, const float* __restrict__ ch2_b,
    const float* __restrict__ ln_h_g, const float* __restrict__ ln_h_b,
    const float* __restrict__ out_w, const float* __restrict__ out_b,
    float* __restrict__ out, int N) {

    __shared__ __align__(16) unsigned short xb[128 * 104];   // 26624 B: x -> h_token -> h_channel
    __shared__ __align__(16) unsigned short ab[128 * 104];   // 26624 B: IN chunks / LN out / tokmix y / (mrs alias)
    __shared__ __align__(16) unsigned short cb[128 * 40];    // 10240 B: ch1-gelu chunk / (stF alias)
    __shared__ int sSel[128];

    const int t = threadIdx.x;
    const int wv = t >> 6;                 // wave = node (and M-row quarter)
    const int l = t & 63;
    const s16x8 zfrag = {0, 0, 0, 0, 0, 0, 0, 0};
    const f32x4 zacc = {0.f, 0.f, 0.f, 0.f};

    const s16x8* headWf_v = (const s16x8*)(wf);
    const s16x8* wg1f_v   = (const s16x8*)(wf + 28672);
    const s16x8* w2f_v    = (const s16x8*)(wf + 79872);
    const s16x8* tok1f_v  = (const s16x8*)(wf + 126464);
    const s16x8* tok2f_v  = (const s16x8*)(wf + 126976);

    // ---- stage selection
    if (t < 128) {
        int node_g = blockIdx.x * NPB + (t >> 5);
        int tok = t & 31;
        sSel[t] = (tok < KTOK && node_g < N) ? sel[node_g * KTOK + tok] : -1;
    }
    __syncthreads();

    // ================= Phase A: head GEMM (K chunked by 64) =================
    const int lrow = t >> 1, lhalf = t & 1;
    int le = sSel[lrow];
    const float* larow = edge_attr + (size_t)(le < 0 ? 0 : le) * 100;
    float ltime = (le >= 0) ? edge_time[le] : 0.f;

    f32x4 hacc[2][7];
    #pragma unroll
    for (int a = 0; a < 2; a++)
        #pragma unroll
        for (int c = 0; c < 7; c++) hacc[a][c] = zacc;

    for (int kc = 0; kc < 4; kc++) {
        // stage IN cols [kc*64, kc*64+64) into ab[.][0..63]
        {
            int gb = kc * 64 + lhalf * 32;
            #pragma unroll
            for (int j = 0; j < 32; j += 4) {
                float v[4];
                int gc = gb + j;
                if (gc >= 100 && gc <= 196) {
                    float4 a4 = *(const float4*)(larow + (gc - 100));
                    v[0] = a4.x; v[1] = a4.y; v[2] = a4.z; v[3] = a4.w;
                } else {
                    #pragma unroll
                    for (int q = 0; q < 4; q++) {
                        int g = gc + q;
                        v[q] = (g < 100) ? __cosf(ltime * exp2f(-0.33554829241286486f * (float)g))
                             : (g < 200) ? larow[g - 100] : 0.f;
                    }
                }
                int lc = lhalf * 32 + j;
                *(unsigned*)&ab[lrow * 104 + lc]     = (unsigned)f2bf(v[0]) | ((unsigned)f2bf(v[1]) << 16);
                *(unsigned*)&ab[lrow * 104 + lc + 2] = (unsigned)f2bf(v[2]) | ((unsigned)f2bf(v[3]) << 16);
            }
        }
        __syncthreads();
        // MFMA: 2 ksteps x 2 mtiles x 7 ntiles
        s16x8 af[2][2];
        #pragma unroll
        for (int mt = 0; mt < 2; mt++)
            #pragma unroll
            for (int kk = 0; kk < 2; kk++)
                af[mt][kk] = *(const s16x8*)&ab[(wv * 32 + mt * 16 + (l & 15)) * 104 + kk * 32 + ((l >> 4) << 3)];
        #pragma unroll
        for (int nt = 0; nt < 7; nt++) {
            #pragma unroll
            for (int kk = 0; kk < 2; kk++) {
                s16x8 bf = headWf_v[((kc * 2 + kk) * 7 + nt) * 64 + l];
                #pragma unroll
                for (int mt = 0; mt < 2; mt++)
                    hacc[mt][nt] = __builtin_amdgcn_mfma_f32_16x16x32_bf16(af[mt][kk], bf, hacc[mt][nt], 0, 0, 0);
            }
        }
        __syncthreads();
    }
    // store x to xb (zero invalid rows; zero pad cols 100..103)
    #pragma unroll
    for (int nt = 0; nt < 7; nt++) {
        int col = nt * 16 + (l & 15);
        float bias = (col < 100) ? head_b[col] : 0.f;
        #pragma unroll
        for (int mt = 0; mt < 2; mt++) {
            #pragma unroll
            for (int jj = 0; jj < 4; jj++) {
                int row = wv * 32 + mt * 16 + ((l >> 4) << 2) + jj;
                if (col < 100)
                    xb[row * 104 + col] = (sSel[row] >= 0) ? f2bf(hacc[mt][nt][jj] + bias) : (unsigned short)0;
                else if (col < 104)
                    xb[row * 104 + col] = 0;
            }
        }
    }
    __syncthreads();

    // ================= Phase B: LN_t -> token mixer =================
    ln_pass(xb, ab, ln_t_g, ln_t_b, nullptr, t);
    __syncthreads();

    {
        // tok1: A[m=ch][k=tok] from ab; load all A-frags first (in-order DS => safe to overwrite after)
        s16x8 av[7];
        #pragma unroll
        for (int mt = 0; mt < 7; mt++) {
            int ch = mt * 16 + (l & 15);
            s16x8 a = zfrag;
            if (ch < 104) {
                #pragma unroll
                for (int i = 0; i < 8; i++) {
                    int k = ((l >> 4) << 3) + i;
                    a[i] = (short)ab[(wv * 32 + k) * 104 + ch];
                }
            }
            av[mt] = a;
        }
        s16x8 b1 = tok1f_v[l];
        float bias1 = ((l & 15) < 15) ? tok1_b[l & 15] : 0.f;
        float yv[7][4];
        #pragma unroll
        for (int mt = 0; mt < 7; mt++) {
            f32x4 y = __builtin_amdgcn_mfma_f32_16x16x32_bf16(av[mt], b1, zacc, 0, 0, 0);
            #pragma unroll
            for (int jj = 0; jj < 4; jj++) yv[mt][jj] = gelu(y[jj] + bias1);
        }
        // write y to yhome in ab: (ch,i) -> ab[wv*32 + ch/4][(ch&3)*16 + i]
        #pragma unroll
        for (int mt = 0; mt < 7; mt++) {
            #pragma unroll
            for (int jj = 0; jj < 4; jj++) {
                int ch = mt * 16 + ((l >> 4) << 2) + jj;
                ab[(wv * 32 + (ch >> 2)) * 104 + (ch & 3) * 16 + (l & 15)] = f2bf(yv[mt][jj]);
            }
        }
    }
    __syncthreads();
    {
        // tok2: A[m=ch][k=i<16] from yhome; D cols = tokens; h_token = D + tok2_b + x (RMW xb)
        s16x8 b2a = tok2f_v[l];
        s16x8 b2b = tok2f_v[64 + l];
        float tb0 = tok2_b[l & 15];
        float tb1 = ((l & 15) < 14) ? tok2_b[16 + (l & 15)] : 0.f;
        #pragma unroll
        for (int mt = 0; mt < 7; mt++) {
            int ch = mt * 16 + (l & 15);
            s16x8 a2 = zfrag;
            int gg = l >> 4;
            if (gg < 2)
                a2 = *(const s16x8*)&ab[(wv * 32 + (ch >> 2)) * 104 + (ch & 3) * 16 + gg * 8];
            f32x4 d0 = __builtin_amdgcn_mfma_f32_16x16x32_bf16(a2, b2a, zacc, 0, 0, 0);
            f32x4 d1 = __builtin_amdgcn_mfma_f32_16x16x32_bf16(a2, b2b, zacc, 0, 0, 0);
            #pragma unroll
            for (int jj = 0; jj < 4; jj++) {
                int chD = mt * 16 + ((l >> 4) << 2) + jj;
                if (chD < 100) {
                    int tok0 = l & 15;
                    int idx0 = (wv * 32 + tok0) * 104 + chD;
                    xb[idx0] = f2bf(bf2f(xb[idx0]) + d0[jj] + tb0);
                    int tok1i = 16 + (l & 15);
                    if (tok1i < 30) {
                        int idx1 = (wv * 32 + tok1i) * 104 + chD;
                        xb[idx1] = f2bf(bf2f(xb[idx1]) + d1[jj] + tb1);
                    }
                }
            }
        }
    }
    __syncthreads();

    // ================= Phase C: LN_c -> ch1 -> gelu -> ch2 (chunked) =================
    ln_pass(xb, ab, ln_c_g, ln_c_b, nullptr, t);
    __syncthreads();

    {
        // persistent A-frags of LN_c: [mt][kk]; kk=3 covers cols 96..103 (only lane-group 0)
        s16x8 a1f[2][4];
        #pragma unroll
        for (int mt = 0; mt < 2; mt++) {
            #pragma unroll
            for (int kk = 0; kk < 4; kk++) {
                s16x8 a = zfrag;
                bool ld = (kk < 3) || ((l >> 4) == 0);
                if (ld)
                    a = *(const s16x8*)&ab[(wv * 32 + mt * 16 + (l & 15)) * 104 + kk * 32 + ((l >> 4) << 3)];
                a1f[mt][kk] = a;
            }
        }
        f32x4 acc2[2][7];
        #pragma unroll
        for (int a = 0; a < 2; a++)
            #pragma unroll
            for (int c = 0; c < 7; c++) acc2[a][c] = zacc;

        for (int hc = 0; hc < 13; hc++) {
            f32x4 acc1[2][2];
            #pragma unroll
            for (int a = 0; a < 2; a++) { acc1[a][0] = zacc; acc1[a][1] = zacc; }
            #pragma unroll
            for (int ntl = 0; ntl < 2; ntl++) {
                int ntg = hc * 2 + ntl;
                if (ntg < 25) {
                    #pragma unroll
                    for (int kk = 0; kk < 4; kk++) {
                        s16x8 bfr = wg1f_v[(kk * 25 + ntg) * 64 + l];
                        #pragma unroll
                        for (int mt = 0; mt < 2; mt++)
                            acc1[mt][ntl] = __builtin_amdgcn_mfma_f32_16x16x32_bf16(a1f[mt][kk], bfr, acc1[mt][ntl], 0, 0, 0);
                    }
                }
            }
            // gelu -> cb chunk
            #pragma unroll
            for (int ntl = 0; ntl < 2; ntl++) {
                int ntg = hc * 2 + ntl;
                if (ntg < 25) {
                    float bias = ch1_b[ntg * 16 + (l & 15)];
                    #pragma unroll
                    for (int mt = 0; mt < 2; mt++) {
                        #pragma unroll
                        for (int jj = 0; jj < 4; jj++) {
                            int row = wv * 32 + mt * 16 + ((l >> 4) << 2) + jj;
                            cb[row * 40 + ntl * 16 + (l & 15)] = f2bf(gelu(acc1[mt][ntl][jj] + bias));
                        }
                    }
                }
            }
            __syncthreads();
            // ch2 partial: K-slice = this chunk (w2f[hc] has zeros for k>=400)
            s16x8 a2f[2];
            #pragma unroll
            for (int mt = 0; mt < 2; mt++)
                a2f[mt] = *(const s16x8*)&cb[(wv * 32 + mt * 16 + (l & 15)) * 40 + ((l >> 4) << 3)];
            #pragma unroll
            for (int nt2 = 0; nt2 < 7; nt2++) {
                s16x8 b2f = w2f_v[(hc * 7 + nt2) * 64 + l];
                #pragma unroll
                for (int mt = 0; mt < 2; mt++)
                    acc2[mt][nt2] = __builtin_amdgcn_mfma_f32_16x16x32_bf16(a2f[mt], b2f, acc2[mt][nt2], 0, 0, 0);
            }
            __syncthreads();
        }
        // h_channel = acc2 + ch2_b + h_token  -> xb
        #pragma unroll
        for (int nt2 = 0; nt2 < 7; nt2++) {
            int col = nt2 * 16 + (l & 15);
            if (col < 100) {
                float bias = ch2_b[col];
                #pragma unroll
                for (int mt = 0; mt < 2; mt++) {
                    #pragma unroll
                    for (int jj = 0; jj < 4; jj++) {
                        int row = wv * 32 + mt * 16 + ((l >> 4) << 2) + jj;
                        int idx = row * 104 + col;
                        xb[idx] = f2bf(acc2[mt][nt2][jj] + bias + bf2f(xb[idx]));
                    }
                }
            }
        }
    }
    __syncthreads();

    // ================= Phase D: LN_h stats -> mean -> out proj =================
    float* sMRS = (float*)ab;              // ab is dead (a1f in regs); 128*2 floats
    ln_pass(xb, ab, ln_h_g, ln_h_b, sMRS, t);
    __syncthreads();

    float* stF = (float*)cb;               // cb dead; 4*100 floats
    #pragma unroll
    for (int p = 0; p < 2; p++) {
        int task = p * 256 + t;
        if (task < 400) {
            int node = task / 100;
            int col = task - node * 100;
            float s = 0.f;
            for (int k = 0; k < KTOK; k++) {
                int row = node * 32 + k;
                float v = bf2f(xb[row * 104 + col]);
                s += (v - sMRS[row * 2]) * sMRS[row * 2 + 1];
            }
            stF[task] = ln_h_g[col] * s * (1.0f / 30.0f) + ln_h_b[col];
        }
    }
    __syncthreads();
    #pragma unroll
    for (int p = 0; p < 2; p++) {
        int task = p * 256 + t;
        if (task < 400) {
            int node = task / 100;
            int o = task - node * 100;
            int ng = blockIdx.x * NPB + node;
            if (ng < N) {
                float a = out_b[o];
                const float* wr = out_w + o * 100;
                const float* tv = stF + node * 100;
                #pragma unroll
                for (int c = 0; c < 100; c += 4) {
                    float4 w4 = *(const float4*)(wr + c);
                    float4 t4 = *(const float4*)(tv + c);
                    a += w4.x * t4.x + w4.y * t4.y + w4.z * t4.z + w4.w * t4.w;
                }
                out[(size_t)ng * 100 + o] = a;
            }
        }
    }
}

// ---------------------------------------------------------------- launch

extern "C" void kernel_launch(void* const* d_in, const int* in_sizes, int n_in,
                              void* d_out, int out_size, void* d_ws, size_t ws_size,
                              hipStream_t stream) {
    const float* edge_attr  = (const float*)d_in[0];
    const float* edge_time  = (const float*)d_in[1];
    const int*   node_batch = (const int*)d_in[2];
    const float* head_w = (const float*)d_in[4];
    const float* head_b = (const float*)d_in[5];
    const float* ln_t_g = (const float*)d_in[6];
    const float* ln_t_b = (const float*)d_in[7];
    const float* tok1_w = (const float*)d_in[8];
    const float* tok1_b = (const float*)d_in[9];
    const float* tok2_w = (const float*)d_in[10];
    const float* tok2_b = (const float*)d_in[11];
    const float* ln_c_g = (const float*)d_in[12];
    const float* ln_c_b = (const float*)d_in[13];
    const float* ch1_w  = (const float*)d_in[14];
    const float* ch1_b  = (const float*)d_in[15];
    const float* ch2_w  = (const float*)d_in[16];
    const float* ch2_b  = (const float*)d_in[17];
    const float* ln_h_g = (const float*)d_in[18];
    const float* ln_h_b = (const float*)d_in[19];
    const float* out_w  = (const float*)d_in[20];
    const float* out_b  = (const float*)d_in[21];
    float* out = (float*)d_out;

    const int E = in_sizes[2];
    const int N = out_size / HIDC;

    int* cnt     = (int*)d_ws;                            // N
    int* cursor  = cnt + N;                               // N
    int* offsets = cursor + N;                            // N
    int* order   = offsets + N;                           // E
    int* sel     = order + E;                             // N*K
    unsigned short* wf = (unsigned short*)(sel + (size_t)N * KTOK);  // 128000 ushort

    hipMemsetAsync(cnt, 0, (size_t)2 * N * sizeof(int), stream);
    count_kernel<<<(E + 255) / 256, 256, 0, stream>>>(node_batch, cnt, E);
    scan_kernel<<<1, SCAN_T, 0, stream>>>(cnt, offsets, N);
    fill_kernel<<<(E + 255) / 256, 256, 0, stream>>>(node_batch, cursor, offsets, order, E);
    select_kernel<<<(N + 255) / 256, 256, 0, stream>>>(cnt, offsets, order, sel, N);
    prep_kernel<<<500, 256, 0, stream>>>(head_w, ch1_w, ch2_w, tok1_w, tok2_w, wf);
    fused_node_kernel<<<(N + NPB - 1) / NPB, 256, 0, stream>>>(
        edge_attr, edge_time, sel, wf, head_b,
        ln_t_g, ln_t_b, tok1_b, tok2_b, ln_c_g, ln_c_b,
        ch1_b, ch2_b, ln_h_g, ln_h_b, out_w, out_b, out, N);
}